// Round 6
// baseline (133.872 us; speedup 1.0000x reference)
//
#include <hip/hip_runtime.h>
#include <math.h>

// Problem constants (fixed by setup_inputs): B=8, C=4, H=W=64, K=8192
#define N_POINTS 32768   // B*H*W
#define KCODES   8192
#define HW       4096
#define CHW      16384

#define NSEG    64                 // code segments (grid.y)
#define SEGLEN  (KCODES / NSEG)    // 128 codes per segment
#define PPT     8                  // points per thread (4 f2 point-pairs)
#define BLOCK   512
#define PTILE   (BLOCK * PPT)      // 4096 points per block
#define GRIDX   (N_POINTS / PTILE) // 8  -> 512 blocks = 2/CU, 4 waves/SIMD

// ws layout: packed u64[32768] @ 0  ((sortable(best_d2)<<32)|best_k)
#define WS_PACKED 0

typedef float f2 __attribute__((ext_vector_type(2)));
typedef float f4 __attribute__((ext_vector_type(4)));

// Packed fp32: 2 IEEE-RN fp32 ops per issue slot; bitwise == scalar per half
// (absmax=0 verified in R3 and R4 with this exact formulation).
static __device__ __forceinline__ f2 pk_mul(f2 a, f2 b) {
  f2 d;
  asm("v_pk_mul_f32 %0, %1, %2" : "=v"(d) : "v"(a), "v"(b));
  return d;
}
static __device__ __forceinline__ f2 pk_add(f2 a, f2 b) {
  f2 d;
  asm("v_pk_add_f32 %0, %1, %2" : "=v"(d) : "v"(a), "v"(b));
  return d;
}

// Bit-exact conv z = W x + b, numpy sequential c-order, no FMA contraction.
__device__ __forceinline__ void compute_z(
    const float* __restrict__ ze, const float* __restrict__ w,
    const float* __restrict__ bias, int n, float zo[4], float& zz) {
  int b = n >> 12, hw = n & 4095;
  const float* p = ze + b * CHW + hw;
  float x0 = p[0], x1 = p[HW], x2 = p[2 * HW], x3 = p[3 * HW];
#pragma unroll
  for (int o = 0; o < 4; ++o) {
    float acc = __fmul_rn(x0, w[o * 4 + 0]);
    acc = __fadd_rn(acc, __fmul_rn(x1, w[o * 4 + 1]));
    acc = __fadd_rn(acc, __fmul_rn(x2, w[o * 4 + 2]));
    acc = __fadd_rn(acc, __fmul_rn(x3, w[o * 4 + 3]));
    zo[o] = __fadd_rn(acc, bias[o]);
  }
  float s = __fmul_rn(zo[0], zo[0]);
  s = __fadd_rn(s, __fmul_rn(zo[1], zo[1]));
  s = __fadd_rn(s, __fmul_rn(zo[2], zo[2]));
  s = __fadd_rn(s, __fmul_rn(zo[3], zo[3]));
  zz = s;
}

// ---------------- Kernel S: segmented scan, point-pair pk-fp32 -------------
// R3/R4 failure isolated: duplicated-z f2 halves ({z,z}) were NOT kept
// resident (VGPR=44 < state size) — the compiler rebuilt each pk operand
// with v_mov pairs (~2.2x VALU bloat, busy 56-58us vs 25.6 modeled).
// Fix: pack TWO POINTS per f2 (distinct halves -> must stay materialized);
// duplicate the per-CODE scalars in LDS instead ({v,v} f2 at stage time),
// so one ds_read_b128 yields two codes' broadcast pairs with zero fixup.
// Cost model per CU: VALU 0.117 instr/pair = 61k cyc (25.6us);
// DS 5 b128 / 2 codes @ PPT=8 = 5120 reads x ~12cyc = 61k cyc (overlapped).
// Rounding chain per half (bitwise == ref, R3/R4-verified):
//   m_i = -2*c_i (exact);  dn = fl(((z0m0+z1m1)+z2m2)+z3m3) = -fl(2*dot)
//   s = (zz + dn) + cn  ==  (|z|^2 - 2*dot) + |c|^2 left-to-right
__global__ __launch_bounds__(512, 4) void vq_scan(
    const float* __restrict__ ze, const float* __restrict__ w,
    const float* __restrict__ bias, const float* __restrict__ cb,
    unsigned long long* __restrict__ packed) {
  __shared__ f2 sm[5][SEGLEN] __attribute__((aligned(16)));  // dup pairs
  int tid = threadIdx.x;
  int k0 = blockIdx.y * SEGLEN;

  // stage segment: threads 0..127 transform one code each into {v,v} pairs
  if (tid < SEGLEN) {
    f4 c = ((const f4*)cb)[k0 + tid];
    float m0 = __fmul_rn(-2.f, c.x), m1 = __fmul_rn(-2.f, c.y);
    float m2 = __fmul_rn(-2.f, c.z), m3 = __fmul_rn(-2.f, c.w);
    float cn = __fmul_rn(c.x, c.x);
    cn = __fadd_rn(cn, __fmul_rn(c.y, c.y));
    cn = __fadd_rn(cn, __fmul_rn(c.z, c.z));
    cn = __fadd_rn(cn, __fmul_rn(c.w, c.w));
    sm[0][tid] = (f2){m0, m0};
    sm[1][tid] = (f2){m1, m1};
    sm[2][tid] = (f2){m2, m2};
    sm[3][tid] = (f2){m3, m3};
    sm[4][tid] = (f2){cn, cn};
  }

  // conv for this thread's 8 points (as 4 point-pairs) while staging lands
  int n0 = blockIdx.x * PTILE + tid;        // points n0 + 512*p, coalesced
  f2 zd[PPT / 2][4], zzd[PPT / 2];
  float best[PPT];
  int bidx[PPT];
#pragma unroll
  for (int i = 0; i < PPT / 2; ++i) {
    float zA[4], zB[4], zzA, zzB;
    compute_z(ze, w, bias, n0 + BLOCK * (2 * i),     zA, zzA);
    compute_z(ze, w, bias, n0 + BLOCK * (2 * i + 1), zB, zzB);
#pragma unroll
    for (int c = 0; c < 4; ++c) zd[i][c] = (f2){zA[c], zB[c]};
    zzd[i] = (f2){zzA, zzB};
    best[2 * i] = INFINITY;     bidx[2 * i] = 0;
    best[2 * i + 1] = INFINITY; bidx[2 * i + 1] = 0;
  }
  __syncthreads();

#pragma unroll 2
  for (int j = 0; j < SEGLEN; j += 2) {     // 2 codes per chunk
    f4 q0 = *(const f4*)&sm[0][j];   // {m0[j],m0[j],m0[j+1],m0[j+1]}
    f4 q1 = *(const f4*)&sm[1][j];
    f4 q2 = *(const f4*)&sm[2][j];
    f4 q3 = *(const f4*)&sm[3][j];
    f4 qn = *(const f4*)&sm[4][j];   // |c|^2 pairs
#pragma unroll
    for (int i = 0; i < PPT / 2; ++i) {
      // code j (ascending before j+1: first-min preserved per point)
      f2 dA = pk_mul(zd[i][0], q0.xy);
      dA = pk_add(dA, pk_mul(zd[i][1], q1.xy));
      dA = pk_add(dA, pk_mul(zd[i][2], q2.xy));
      dA = pk_add(dA, pk_mul(zd[i][3], q3.xy));
      f2 sA = pk_add(pk_add(zzd[i], dA), qn.xy);
      if (sA.x < best[2 * i])     { best[2 * i] = sA.x;     bidx[2 * i] = j; }
      if (sA.y < best[2 * i + 1]) { best[2 * i + 1] = sA.y; bidx[2 * i + 1] = j; }
      // code j+1
      f2 dB = pk_mul(zd[i][0], q0.zw);
      dB = pk_add(dB, pk_mul(zd[i][1], q1.zw));
      dB = pk_add(dB, pk_mul(zd[i][2], q2.zw));
      dB = pk_add(dB, pk_mul(zd[i][3], q3.zw));
      f2 sB = pk_add(pk_add(zzd[i], dB), qn.zw);
      if (sB.x < best[2 * i])     { best[2 * i] = sB.x;     bidx[2 * i] = j + 1; }
      if (sB.y < best[2 * i + 1]) { best[2 * i + 1] = sB.y; bidx[2 * i + 1] = j + 1; }
    }
  }

#pragma unroll
  for (int p = 0; p < PPT; ++p) {
    // pack (sortable float, global k): u64 min == (min d2, then min k)
    unsigned int u = __float_as_uint(best[p]);
    unsigned int so = (u & 0x80000000u) ? ~u : (u | 0x80000000u);
    unsigned long long key =
        ((unsigned long long)so << 32) | (unsigned int)(k0 + bidx[p]);
    atomicMin(&packed[n0 + BLOCK * p], key);
  }
}

// ---------------- Kernel F: decode, gather, latent write, loss -------------
// Unchanged from the 115.8us baseline (bit-exact, absmax=0 proven).
__global__ __launch_bounds__(256) void vq_finish(
    const float* __restrict__ ze, const float* __restrict__ w,
    const float* __restrict__ bias, const float* __restrict__ cb,
    const unsigned long long* __restrict__ packed, float* __restrict__ out) {
  int n = blockIdx.x * 256 + threadIdx.x;
  int bidx = (unsigned int)(packed[n] & 0xFFFFFFFFull);
  float4 c = ((const float4*)cb)[bidx];     // bit-exact gather (16B aligned)
  int b = n >> 12, hw = n & 4095;
  float* o = out + b * CHW + hw;
  o[0] = c.x; o[HW] = c.y; o[2 * HW] = c.z; o[3 * HW] = c.w;
  float z[4], zz;
  compute_z(ze, w, bias, n, z, zz);
  float d0 = c.x - z[0], d1 = c.y - z[1], d2 = c.z - z[2], d3 = c.w - z[3];
  float e = d0 * d0 + d1 * d1 + d2 * d2 + d3 * d3;
#pragma unroll
  for (int off = 32; off > 0; off >>= 1) e += __shfl_down(e, off, 64);
  __shared__ float sred[4];
  if ((threadIdx.x & 63) == 0) sred[threadIdx.x >> 6] = e;
  __syncthreads();
  if (threadIdx.x == 0) {
    float t = (sred[0] + sred[1]) + (sred[2] + sred[3]);
    // q_loss = (1 + BETA) * mean over 131072 elements
    atomicAdd(out + (N_POINTS * 4), t * (1.25f / 131072.f));
  }
}

extern "C" void kernel_launch(void* const* d_in, const int* in_sizes, int n_in,
                              void* d_out, int out_size, void* d_ws, size_t ws_size,
                              hipStream_t stream) {
  const float* ze   = (const float*)d_in[0];  // z_e_in [8,4,64,64]
  const float* w    = (const float*)d_in[1];  // pq_w [4,4]
  const float* bias = (const float*)d_in[2];  // pq_b [4]
  const float* cb   = (const float*)d_in[3];  // codebook [8192,4]

  unsigned long long* packed =
      (unsigned long long*)((char*)d_ws + WS_PACKED);
  float* out = (float*)d_out;

  // poison packed (0xFF bytes == u64 all-ones == sortable max) + zero loss
  hipMemsetAsync(packed, 0xFF, N_POINTS * sizeof(unsigned long long), stream);
  hipMemsetAsync((char*)d_out + (size_t)N_POINTS * 4 * sizeof(float), 0,
                 sizeof(float), stream);
  vq_scan<<<dim3(GRIDX, NSEG), BLOCK, 0, stream>>>(ze, w, bias, cb, packed);
  vq_finish<<<128, 256, 0, stream>>>(ze, w, bias, cb, packed, out);
}

// Round 7
// 132.799 us; speedup vs baseline: 1.0081x; 1.0081x over previous
//
#include <hip/hip_runtime.h>
#include <math.h>

// Problem constants (fixed by setup_inputs): B=8, C=4, H=W=64, K=8192
#define N_POINTS 32768   // B*H*W
#define KCODES   8192
#define HW       4096
#define CHW      16384
#define NSEG     32
#define SEGLEN   (KCODES / NSEG)   // 256 codes per segment
#define PPT      4                 // points per thread in vq_scan
#define PTILE    (256 * PPT)       // 1024 points per block

// ws layout (bytes):
//   cb2    float4[8192]  @ 0        (2*codebook — exact doubling)
//   cbn    float [8192]  @ 131072   (|c|^2, numpy rounding order; 16B aligned)
//   packed u64   [32768] @ 163840   ((sortable(best_d2)<<32)|best_k per point)
#define WS_CB2    0
#define WS_CBN    131072
#define WS_PACKED 163840

// Bit-exact conv z = W x + b, numpy sequential c-order, no FMA contraction.
__device__ __forceinline__ void compute_z(
    const float* __restrict__ ze, const float* __restrict__ w,
    const float* __restrict__ bias, int n, float zo[4], float& zz) {
  int b = n >> 12, hw = n & 4095;
  const float* p = ze + b * CHW + hw;
  float x0 = p[0], x1 = p[HW], x2 = p[2 * HW], x3 = p[3 * HW];
#pragma unroll
  for (int o = 0; o < 4; ++o) {
    float acc = __fmul_rn(x0, w[o * 4 + 0]);
    acc = __fadd_rn(acc, __fmul_rn(x1, w[o * 4 + 1]));
    acc = __fadd_rn(acc, __fmul_rn(x2, w[o * 4 + 2]));
    acc = __fadd_rn(acc, __fmul_rn(x3, w[o * 4 + 3]));
    zo[o] = __fadd_rn(acc, bias[o]);
  }
  float s = __fmul_rn(zo[0], zo[0]);
  s = __fadd_rn(s, __fmul_rn(zo[1], zo[1]));
  s = __fadd_rn(s, __fmul_rn(zo[2], zo[2]));
  s = __fadd_rn(s, __fmul_rn(zo[3], zo[3]));
  zz = s;
}

// ---------------- Kernel P: init packed + codebook transform + loss zero ---
__global__ __launch_bounds__(256) void vq_init(
    const float* __restrict__ cb, float4* __restrict__ cb2,
    float* __restrict__ cbn, unsigned long long* __restrict__ packed,
    float* __restrict__ out) {
  int t = blockIdx.x * 256 + threadIdx.x;   // grid covers 32768
  packed[t] = 0xFFFFFFFFFFFFFFFFull;        // ws is re-poisoned every call
  if (t < KCODES) {
    float c0 = cb[t * 4 + 0], c1 = cb[t * 4 + 1];
    float c2 = cb[t * 4 + 2], c3 = cb[t * 4 + 3];
    // doubling by 2 is exact: sum(2*z*c) == 2*sum(z*c) bitwise
    cb2[t] = make_float4(2.f * c0, 2.f * c1, 2.f * c2, 2.f * c3);
    float s = __fmul_rn(c0, c0);
    s = __fadd_rn(s, __fmul_rn(c1, c1));
    s = __fadd_rn(s, __fmul_rn(c2, c2));
    s = __fadd_rn(s, __fmul_rn(c3, c3));
    cbn[t] = s;
  }
  if (t == 0) out[N_POINTS * 4] = 0.f;      // zero the q_loss slot
}

// ---------------- Kernel S: fused conv + argmin scan, LDS + reg dbuf -------
// Arithmetic verbatim from the proven 115.8us baseline (12 scalar slots/pair
// = the bit-exact floor; R3-R6 proved v_pk_f32 is 4-cyc on gfx950 -> no
// packing win possible: fp32 peak 157.3TF == scalar rate). Only the segment
// geometry changed: NSEG 64->32 (SEGLEN 256, PPT 4) halves the atomic tail,
// redundant conv work, and block prologue count at unchanged grid (1024
// blocks, 16 waves/CU) and unchanged per-pair VALU cost. DS doubles per pair
// but stays sub-critical (25.5us/CU vs 41us VALU).
__global__ __launch_bounds__(256, 3) void vq_scan(
    const float* __restrict__ ze, const float* __restrict__ w,
    const float* __restrict__ bias, const float4* __restrict__ cb2,
    const float* __restrict__ cbn, unsigned long long* __restrict__ packed) {
  __shared__ float4 s_c[SEGLEN];            // 2*codebook segment (4096 B)
  __shared__ float  s_n[SEGLEN];            // |c|^2 segment (1024 B)
  int tid = threadIdx.x;
  int k0 = blockIdx.y * SEGLEN;
  // cooperative stage: 1024 dwords of cb2 (4/thread) + 256 dwords of cbn
  ((float*)s_c)[tid]       = ((const float*)(cb2 + k0))[tid];
  ((float*)s_c)[tid + 256] = ((const float*)(cb2 + k0))[tid + 256];
  ((float*)s_c)[tid + 512] = ((const float*)(cb2 + k0))[tid + 512];
  ((float*)s_c)[tid + 768] = ((const float*)(cb2 + k0))[tid + 768];
  s_n[tid] = cbn[k0 + tid];
  // conv for this thread's 4 points while the staging loads land
  int n0 = blockIdx.x * PTILE + tid;        // points n0 + 256*p, coalesced
  float z[PPT][4], zz[PPT], best[PPT];
  int bidx[PPT];
#pragma unroll
  for (int p = 0; p < PPT; ++p) {
    compute_z(ze, w, bias, n0 + 256 * p, z[p], zz[p]);
    best[p] = INFINITY;
    bidx[p] = 0;
  }
  __syncthreads();
  // ---- double-buffered chunk loop (4 codes/chunk, ascending k) ----
  float4 cA[4], nA;
  cA[0] = s_c[0]; cA[1] = s_c[1]; cA[2] = s_c[2]; cA[3] = s_c[3];
  nA = *(const float4*)&s_n[0];
  for (int kc = 0; kc < SEGLEN; kc += 4) {
    int kn = (kc + 4) & (SEGLEN - 1);       // wraps harmlessly on last iter
    float4 cB[4], nB;
    cB[0] = s_c[kn + 0]; cB[1] = s_c[kn + 1];
    cB[2] = s_c[kn + 2]; cB[3] = s_c[kn + 3];
    nB = *(const float4*)&s_n[kn];
    float cnr[4] = {nA.x, nA.y, nA.z, nA.w};
#pragma unroll
    for (int r = 0; r < 4; ++r) {
      int kk = k0 + kc + r;                 // ascending k: strict < = first-min
#pragma unroll
      for (int p = 0; p < PPT; ++p) {
        // 2*dot with numpy's sequential rounding order (doubling is exact)
        float d = __fmul_rn(z[p][0], cA[r].x);
        d = __fadd_rn(d, __fmul_rn(z[p][1], cA[r].y));
        d = __fadd_rn(d, __fmul_rn(z[p][2], cA[r].z));
        d = __fadd_rn(d, __fmul_rn(z[p][3], cA[r].w));
        // ref: (|z|^2 - 2*dot) + |c|^2, left-to-right
        float s = __fadd_rn(__fsub_rn(zz[p], d), cnr[r]);
        if (s < best[p]) { best[p] = s; bidx[p] = kk; }
      }
    }
    cA[0] = cB[0]; cA[1] = cB[1]; cA[2] = cB[2]; cA[3] = cB[3];
    nA = nB;
  }
#pragma unroll
  for (int p = 0; p < PPT; ++p) {
    // pack (sortable float, k): u64 min == (min value, then min k)
    unsigned int u = __float_as_uint(best[p]);
    unsigned int so = (u & 0x80000000u) ? ~u : (u | 0x80000000u);
    unsigned long long key =
        ((unsigned long long)so << 32) | (unsigned int)bidx[p];
    atomicMin(&packed[n0 + 256 * p], key);
  }
}

// ---------------- Kernel F: decode, gather, latent write, loss -------------
__global__ __launch_bounds__(256) void vq_finish(
    const float* __restrict__ ze, const float* __restrict__ w,
    const float* __restrict__ bias, const float* __restrict__ cb,
    const unsigned long long* __restrict__ packed, float* __restrict__ out) {
  int n = blockIdx.x * 256 + threadIdx.x;
  int bidx = (unsigned int)(packed[n] & 0xFFFFFFFFull);
  float4 c = ((const float4*)cb)[bidx];     // bit-exact gather (16B aligned)
  int b = n >> 12, hw = n & 4095;
  float* o = out + b * CHW + hw;
  o[0] = c.x; o[HW] = c.y; o[2 * HW] = c.z; o[3 * HW] = c.w;
  float z[4], zz;
  compute_z(ze, w, bias, n, z, zz);
  float d0 = c.x - z[0], d1 = c.y - z[1], d2 = c.z - z[2], d3 = c.w - z[3];
  float e = d0 * d0 + d1 * d1 + d2 * d2 + d3 * d3;
#pragma unroll
  for (int off = 32; off > 0; off >>= 1) e += __shfl_down(e, off, 64);
  __shared__ float sred[4];
  if ((threadIdx.x & 63) == 0) sred[threadIdx.x >> 6] = e;
  __syncthreads();
  if (threadIdx.x == 0) {
    float t = (sred[0] + sred[1]) + (sred[2] + sred[3]);
    // q_loss = (1 + BETA) * mean over 131072 elements
    atomicAdd(out + (N_POINTS * 4), t * (1.25f / 131072.f));
  }
}

extern "C" void kernel_launch(void* const* d_in, const int* in_sizes, int n_in,
                              void* d_out, int out_size, void* d_ws, size_t ws_size,
                              hipStream_t stream) {
  const float* ze   = (const float*)d_in[0];  // z_e_in [8,4,64,64]
  const float* w    = (const float*)d_in[1];  // pq_w [4,4]
  const float* bias = (const float*)d_in[2];  // pq_b [4]
  const float* cb   = (const float*)d_in[3];  // codebook [8192,4]

  char* ws = (char*)d_ws;
  float4* cb2 = (float4*)(ws + WS_CB2);
  float*  cbn = (float*)(ws + WS_CBN);
  unsigned long long* packed = (unsigned long long*)(ws + WS_PACKED);
  float* out = (float*)d_out;

  vq_init<<<128, 256, 0, stream>>>(cb, cb2, cbn, packed, out);
  vq_scan<<<dim3(N_POINTS / PTILE, NSEG), 256, 0, stream>>>(
      ze, w, bias, cb2, cbn, packed);
  vq_finish<<<128, 256, 0, stream>>>(ze, w, bias, cb, packed, out);
}

// Round 8
// 117.243 us; speedup vs baseline: 1.1418x; 1.1327x over previous
//
#include <hip/hip_runtime.h>
#include <math.h>

// Problem constants (fixed by setup_inputs): B=8, C=4, H=W=64, K=8192
#define N_POINTS 32768   // B*H*W
#define KCODES   8192
#define HW       4096
#define CHW      16384
#define NSEG     64
#define SEGLEN   (KCODES / NSEG)   // 128 codes per segment
#define PPT      8                 // points per thread (R0-proven)
#define PTILE    (64 * PPT)        // 512 points per 1-wave block
#define GRIDX    (N_POINTS / PTILE) // 64 -> grid 64x64 = 4096 blocks

// ws layout: packed u64[32768] @ 0  ((sortable(best_d2)<<32)|best_k)
#define WS_PACKED 0

// Bit-exact conv z = W x + b, numpy sequential c-order, no FMA contraction.
__device__ __forceinline__ void compute_z(
    const float* __restrict__ ze, const float* __restrict__ w,
    const float* __restrict__ bias, int n, float zo[4], float& zz) {
  int b = n >> 12, hw = n & 4095;
  const float* p = ze + b * CHW + hw;
  float x0 = p[0], x1 = p[HW], x2 = p[2 * HW], x3 = p[3 * HW];
#pragma unroll
  for (int o = 0; o < 4; ++o) {
    float acc = __fmul_rn(x0, w[o * 4 + 0]);
    acc = __fadd_rn(acc, __fmul_rn(x1, w[o * 4 + 1]));
    acc = __fadd_rn(acc, __fmul_rn(x2, w[o * 4 + 2]));
    acc = __fadd_rn(acc, __fmul_rn(x3, w[o * 4 + 3]));
    zo[o] = __fadd_rn(acc, bias[o]);
  }
  float s = __fmul_rn(zo[0], zo[0]);
  s = __fadd_rn(s, __fmul_rn(zo[1], zo[1]));
  s = __fadd_rn(s, __fmul_rn(zo[2], zo[2]));
  s = __fadd_rn(s, __fmul_rn(zo[3], zo[3]));
  zz = s;
}

// ---------------- Kernel S: 1-wave barrier-free scan -----------------------
// Inner loop VERBATIM from the proven 115.96us baseline (R0). R1-R7 lesson:
// any reshaping of the inner arithmetic (pk-f32, PPT=4, scalar-broadcast,
// vector-broadcast) inflates emitted VALU 1.6-2.2x; R0's form is 90% of the
// 41us bit-exact issue floor (busy 45.4us). This round attacks only the
// wall-busy gap (14us): 1-wave blocks remove __syncthreads entirely, 4096
// blocks (16 rounds/CU) shrink the drain tail 4x, and the init kernel is
// folded in (each wave transforms its own 128-code segment: 2c exact, |c|^2
// in numpy order) — occupancy unchanged at 16 waves/CU (4/SIMD).
__global__ __launch_bounds__(64, 4) void vq_scan(
    const float* __restrict__ ze, const float* __restrict__ w,
    const float* __restrict__ bias, const float* __restrict__ cb,
    unsigned long long* __restrict__ packed) {
  __shared__ float4 s_c[SEGLEN];            // 2*codebook segment (2048 B)
  __shared__ float  s_n[SEGLEN];            // |c|^2 segment (512 B)
  int lane = threadIdx.x;                   // 0..63, one wave per block
  int k0 = blockIdx.y * SEGLEN;
  // transform+stage 2 codes per lane (doubling by 2 is exact bitwise)
#pragma unroll
  for (int q = 0; q < 2; ++q) {
    float4 c = ((const float4*)cb)[k0 + 64 * q + lane];
    s_c[64 * q + lane] =
        make_float4(2.f * c.x, 2.f * c.y, 2.f * c.z, 2.f * c.w);
    float s = __fmul_rn(c.x, c.x);
    s = __fadd_rn(s, __fmul_rn(c.y, c.y));
    s = __fadd_rn(s, __fmul_rn(c.z, c.z));
    s = __fadd_rn(s, __fmul_rn(c.w, c.w));
    s_n[64 * q + lane] = s;
  }
  // conv for this wave's 8 points while the staging writes land
  int n0 = blockIdx.x * PTILE + lane;       // points n0 + 64*p, coalesced
  float z[PPT][4], zz[PPT], best[PPT];
  int bidx[PPT];
#pragma unroll
  for (int p = 0; p < PPT; ++p) {
    compute_z(ze, w, bias, n0 + 64 * p, z[p], zz[p]);
    best[p] = INFINITY;
    bidx[p] = 0;
  }
  __builtin_amdgcn_wave_barrier();          // same-wave ds order; no s_barrier
  // ---- double-buffered chunk loop (4 codes/chunk, ascending k) ----
  float4 cA[4], nA;
  cA[0] = s_c[0]; cA[1] = s_c[1]; cA[2] = s_c[2]; cA[3] = s_c[3];
  nA = *(const float4*)&s_n[0];
  for (int kc = 0; kc < SEGLEN; kc += 4) {
    int kn = (kc + 4) & (SEGLEN - 1);       // wraps harmlessly on last iter
    float4 cB[4], nB;
    cB[0] = s_c[kn + 0]; cB[1] = s_c[kn + 1];
    cB[2] = s_c[kn + 2]; cB[3] = s_c[kn + 3];
    nB = *(const float4*)&s_n[kn];
    float cnr[4] = {nA.x, nA.y, nA.z, nA.w};
#pragma unroll
    for (int r = 0; r < 4; ++r) {
      int kk = k0 + kc + r;                 // ascending k: strict < = first-min
#pragma unroll
      for (int p = 0; p < PPT; ++p) {
        // 2*dot with numpy's sequential rounding order (doubling is exact)
        float d = __fmul_rn(z[p][0], cA[r].x);
        d = __fadd_rn(d, __fmul_rn(z[p][1], cA[r].y));
        d = __fadd_rn(d, __fmul_rn(z[p][2], cA[r].z));
        d = __fadd_rn(d, __fmul_rn(z[p][3], cA[r].w));
        // ref: (|z|^2 - 2*dot) + |c|^2, left-to-right
        float s = __fadd_rn(__fsub_rn(zz[p], d), cnr[r]);
        if (s < best[p]) { best[p] = s; bidx[p] = kk; }
      }
    }
    cA[0] = cB[0]; cA[1] = cB[1]; cA[2] = cB[2]; cA[3] = cB[3];
    nA = nB;
  }
#pragma unroll
  for (int p = 0; p < PPT; ++p) {
    // pack (sortable float, k): u64 min == (min value, then min k)
    unsigned int u = __float_as_uint(best[p]);
    unsigned int so = (u & 0x80000000u) ? ~u : (u | 0x80000000u);
    unsigned long long key =
        ((unsigned long long)so << 32) | (unsigned int)bidx[p];
    atomicMin(&packed[n0 + 64 * p], key);
  }
}

// ---------------- Kernel F: decode, gather, latent write, loss -------------
// Unchanged from the 115.96us baseline (bit-exact, absmax=0 proven).
__global__ __launch_bounds__(256) void vq_finish(
    const float* __restrict__ ze, const float* __restrict__ w,
    const float* __restrict__ bias, const float* __restrict__ cb,
    const unsigned long long* __restrict__ packed, float* __restrict__ out) {
  int n = blockIdx.x * 256 + threadIdx.x;
  int bidx = (unsigned int)(packed[n] & 0xFFFFFFFFull);
  float4 c = ((const float4*)cb)[bidx];     // bit-exact gather (16B aligned)
  int b = n >> 12, hw = n & 4095;
  float* o = out + b * CHW + hw;
  o[0] = c.x; o[HW] = c.y; o[2 * HW] = c.z; o[3 * HW] = c.w;
  float z[4], zz;
  compute_z(ze, w, bias, n, z, zz);
  float d0 = c.x - z[0], d1 = c.y - z[1], d2 = c.z - z[2], d3 = c.w - z[3];
  float e = d0 * d0 + d1 * d1 + d2 * d2 + d3 * d3;
#pragma unroll
  for (int off = 32; off > 0; off >>= 1) e += __shfl_down(e, off, 64);
  __shared__ float sred[4];
  if ((threadIdx.x & 63) == 0) sred[threadIdx.x >> 6] = e;
  __syncthreads();
  if (threadIdx.x == 0) {
    float t = (sred[0] + sred[1]) + (sred[2] + sred[3]);
    // q_loss = (1 + BETA) * mean over 131072 elements
    atomicAdd(out + (N_POINTS * 4), t * (1.25f / 131072.f));
  }
}

extern "C" void kernel_launch(void* const* d_in, const int* in_sizes, int n_in,
                              void* d_out, int out_size, void* d_ws, size_t ws_size,
                              hipStream_t stream) {
  const float* ze   = (const float*)d_in[0];  // z_e_in [8,4,64,64]
  const float* w    = (const float*)d_in[1];  // pq_w [4,4]
  const float* bias = (const float*)d_in[2];  // pq_b [4]
  const float* cb   = (const float*)d_in[3];  // codebook [8192,4]

  unsigned long long* packed =
      (unsigned long long*)((char*)d_ws + WS_PACKED);
  float* out = (float*)d_out;

  // poison packed (0xFF == u64 max == sortable max) + zero loss (R4-proven)
  hipMemsetAsync(packed, 0xFF, N_POINTS * sizeof(unsigned long long), stream);
  hipMemsetAsync((char*)d_out + (size_t)N_POINTS * 4 * sizeof(float), 0,
                 sizeof(float), stream);
  vq_scan<<<dim3(GRIDX, NSEG), 64, 0, stream>>>(ze, w, bias, cb, packed);
  vq_finish<<<128, 256, 0, stream>>>(ze, w, bias, cb, packed, out);
}